// Round 7
// baseline (169.173 us; speedup 1.0000x reference)
//
#include <hip/hip_runtime.h>
#include <hip/hip_bf16.h>
#include <stdint.h>

#define SEQ 4096
#define DIN 1024
#define DOUT 1024

typedef __bf16 bf16;
typedef __bf16 bf16x4v __attribute__((ext_vector_type(4)));
typedef __bf16 bf16x8v __attribute__((ext_vector_type(8)));
typedef float f32x4 __attribute__((ext_vector_type(4)));

#define AS1 __attribute__((address_space(1)))
#define AS3 __attribute__((address_space(3)))

__device__ __forceinline__ void load_lds16(const void* g, void* l) {
  __builtin_amdgcn_global_load_lds((const AS1 uint32_t*)g, (AS3 uint32_t*)l, 16, 0, 0);
}
__device__ __forceinline__ int imin(int a, int b) { return a < b ? a : b; }

// m204 bijective XCD swizzle
__device__ __forceinline__ int xcd_swz(int orig, int nwg) {
  const int q = nwg >> 3, r = nwg & 7;
  const int x = orig & 7, idx = orig >> 3;
  return (x < r ? x * (q + 1) : r * (q + 1) + (x - r) * q) + idx;
}

// ---------------- fused cast fp32 -> bf16 for x, Wq, Wk, Wv (exact 1D grid) ---
__global__ __launch_bounds__(256) void cast_all_kernel(
    const float* __restrict__ x, const float* __restrict__ wq,
    const float* __restrict__ wk, const float* __restrict__ wv,
    bf16* __restrict__ xb, bf16* __restrict__ wqb,
    bf16* __restrict__ wkb, bf16* __restrict__ wvb) {
  const int id = blockIdx.x;
  const float* in; bf16* out; int blk;
  if (id < 4096) {
    in = x; out = xb; blk = id;
  } else {
    const int w = (id - 4096) >> 10;
    blk = (id - 4096) & 1023;
    in = (w == 0) ? wq : (w == 1) ? wk : wv;
    out = (w == 0) ? wqb : (w == 1) ? wkb : wvb;
  }
  const int i = (blk * 256 + threadIdx.x) * 4;
  float4 v = *reinterpret_cast<const float4*>(in + i);
  bf16x4v o;
  o[0] = (bf16)v.x; o[1] = (bf16)v.y; o[2] = (bf16)v.z; o[3] = (bf16)v.w;
  *reinterpret_cast<bf16x4v*>(out + i) = o;
}

// =============== 256x256 BT-GEMM core, BK=64, phase-split counted-vmcnt =======
// C[256x256] += A[brow..][k] * B[bcol..][k]^T, K-tiles [kt0, kt0+ktn) of 64.
// 512 threads = 8 waves (2M x 4N); wave out 128x64 = acc[mh2][nh2][mt4][nt2].
// LDS per dbuf (64KB): A-half0 @0, A-half1 @16384, B-half0 @32768, B-half1 @49152;
// half = 128 rows x 128B, XOR-swizzled (slot(r,c) = global (r, c^((r&7)<<4))).
// STAGING: each wave stages ONLY the two halves it reads (A-half[wm], B-half[wn>>1]),
// 8 calls/wave/K-tile in order [Ac0,Ac1 | Bc0,Bc2 | Bc1,Bc3,Ac2,Ac3] issued in
// phases P1/P2/P3. Call (X,c) of a wave covers rows c*32 + grp*8 + (lane>>3), so
// "first k calls of EVERY wave" (vmcnt+barrier) = a row-prefix of each half:
//   P1 needs A rows[0,64)+B rows[brow0,brow0+32)  <- calls 1-4  -> vmcnt(4)
//   P2 needs B rows[brow0+32,brow0+64)            <- calls 5-6  -> vmcnt(4)
//   P3 needs A rows[64,128)                       <- calls 7-8  -> vmcnt(4)
// Loads are never drained to 0 in the loop; 4-6 stay in flight across barriers.
struct G256 {
  const char *gA, *gB;
  size_t sA32, sB32;      // 32 global rows in bytes
  char* lds;
  uint32_t ldsA, ldsB;    // per-thread dest offset within a dbuf
};

__device__ __forceinline__ void stA(const G256& g, int sd, int kt, int c) {
  load_lds16(g.gA + (size_t)kt * 128 + (size_t)c * g.sA32,
             g.lds + sd * 65536 + g.ldsA + c * 4096);
}
__device__ __forceinline__ void stB(const G256& g, int sd, int kt, int c) {
  load_lds16(g.gB + (size_t)kt * 128 + (size_t)c * g.sB32,
             g.lds + sd * 65536 + g.ldsB + c * 4096);
}

#define VMCNT4_BAR()                                   \
  asm volatile("s_waitcnt vmcnt(4)" ::: "memory");     \
  __builtin_amdgcn_s_barrier();                        \
  __builtin_amdgcn_sched_barrier(0);

__device__ __forceinline__ void gemm256_core(const bf16* __restrict__ A,
                                             const bf16* __restrict__ B,
                                             int lda, int ldb, int brow, int bcol,
                                             int kt0, int ktn,
                                             f32x4 acc[2][2][4][2], char* lds) {
  const int tid = threadIdx.x;
  const int lane = tid & 63, lrow = lane & 15, lkg = lane >> 4;
  const int wave = tid >> 6, wm = wave >> 2, wn = wave & 3;
  const int bh = wn >> 1, gg = wm * 2 + (wn & 1);

  const size_t lda2 = (size_t)lda * 2, ldb2 = (size_t)ldb * 2;
  const int colByte = ((lane & 7) ^ (lane >> 3)) << 4;  // pre-swizzled src col
  G256 g;
  g.sA32 = 32 * lda2; g.sB32 = 32 * ldb2;
  g.gA = (const char*)A + (size_t)(brow + wm * 128 + wn * 8 + (lane >> 3)) * lda2 + colByte;
  g.gB = (const char*)B + (size_t)(bcol + bh * 128 + gg * 8 + (lane >> 3)) * ldb2 + colByte;
  g.lds = lds;
  g.ldsA = wm * 16384 + wn * 1024 + lane * 16;
  g.ldsB = 32768 + bh * 16384 + gg * 1024 + lane * 16;

  const int aReg = wm * 16384;
  const int bReg = 32768 + bh * 16384;
  const int brow0 = (wn & 1) * 64;
  const int swz = (lrow & 7) << 4;

  // prologue: stage tile kt0 in canonical call order (no wait here)
  stA(g, 0, kt0, 0); stA(g, 0, kt0, 1);
  stB(g, 0, kt0, 0); stB(g, 0, kt0, 2);
  stB(g, 0, kt0, 1); stB(g, 0, kt0, 3);
  stA(g, 0, kt0, 2); stA(g, 0, kt0, 3);

  for (int t = 0; t < ktn; ++t) {
    const int d = t & 1, sd = d ^ 1;
    const char* db = lds + d * 65536;
    const int knxt = kt0 + imin(t + 1, ktn - 1);  // clamped dup on last iter

    bf16x8v a0[4][2], a1[4][2], b0[2][2], b1[2][2];

    // ---- P1: quadrant (mh0 x b-lo) ----
    VMCNT4_BAR();
#pragma unroll
    for (int mt = 0; mt < 4; ++mt)
#pragma unroll
      for (int ks = 0; ks < 2; ++ks)
        a0[mt][ks] = *(const bf16x8v*)(db + aReg + (mt * 16 + lrow) * 128 + ((ks * 64 + lkg * 16) ^ swz));
#pragma unroll
    for (int nt = 0; nt < 2; ++nt)
#pragma unroll
      for (int ks = 0; ks < 2; ++ks)
        b0[nt][ks] = *(const bf16x8v*)(db + bReg + (brow0 + nt * 16 + lrow) * 128 + ((ks * 64 + lkg * 16) ^ swz));
    stA(g, sd, knxt, 0); stA(g, sd, knxt, 1);
    __builtin_amdgcn_s_setprio(1);
#pragma unroll
    for (int mt = 0; mt < 4; ++mt)
#pragma unroll
      for (int nt = 0; nt < 2; ++nt)
#pragma unroll
        for (int ks = 0; ks < 2; ++ks)
          acc[0][0][mt][nt] = __builtin_amdgcn_mfma_f32_16x16x32_bf16(a0[mt][ks], b0[nt][ks], acc[0][0][mt][nt], 0, 0, 0);
    __builtin_amdgcn_s_setprio(0);
    __builtin_amdgcn_sched_barrier(0);

    // ---- P2: quadrant (mh0 x b-hi) ----
    VMCNT4_BAR();
#pragma unroll
    for (int nt = 0; nt < 2; ++nt)
#pragma unroll
      for (int ks = 0; ks < 2; ++ks)
        b1[nt][ks] = *(const bf16x8v*)(db + bReg + (brow0 + 32 + nt * 16 + lrow) * 128 + ((ks * 64 + lkg * 16) ^ swz));
    stB(g, sd, knxt, 0); stB(g, sd, knxt, 2);
    __builtin_amdgcn_s_setprio(1);
#pragma unroll
    for (int mt = 0; mt < 4; ++mt)
#pragma unroll
      for (int nt = 0; nt < 2; ++nt)
#pragma unroll
        for (int ks = 0; ks < 2; ++ks)
          acc[0][1][mt][nt] = __builtin_amdgcn_mfma_f32_16x16x32_bf16(a0[mt][ks], b1[nt][ks], acc[0][1][mt][nt], 0, 0, 0);
    __builtin_amdgcn_s_setprio(0);
    __builtin_amdgcn_sched_barrier(0);

    // ---- P3: quadrants (mh1 x b-hi) + (mh1 x b-lo) ----
    VMCNT4_BAR();
#pragma unroll
    for (int mt = 0; mt < 4; ++mt)
#pragma unroll
      for (int ks = 0; ks < 2; ++ks)
        a1[mt][ks] = *(const bf16x8v*)(db + aReg + ((64 + mt * 16 + lrow) * 128) + ((ks * 64 + lkg * 16) ^ swz));
    stB(g, sd, knxt, 1); stB(g, sd, knxt, 3);
    stA(g, sd, knxt, 2); stA(g, sd, knxt, 3);
    __builtin_amdgcn_s_setprio(1);
#pragma unroll
    for (int mt = 0; mt < 4; ++mt)
#pragma unroll
      for (int nt = 0; nt < 2; ++nt)
#pragma unroll
        for (int ks = 0; ks < 2; ++ks) {
          acc[1][1][mt][nt] = __builtin_amdgcn_mfma_f32_16x16x32_bf16(a1[mt][ks], b1[nt][ks], acc[1][1][mt][nt], 0, 0, 0);
          acc[1][0][mt][nt] = __builtin_amdgcn_mfma_f32_16x16x32_bf16(a1[mt][ks], b0[nt][ks], acc[1][0][mt][nt], 0, 0, 0);
        }
    __builtin_amdgcn_s_setprio(0);
    __builtin_amdgcn_sched_barrier(0);
  }
}

#define ACC256_INIT()                         \
  f32x4 acc[2][2][4][2];                      \
  {                                           \
    f32x4 z = {0.f, 0.f, 0.f, 0.f};           \
    for (int a1 = 0; a1 < 2; ++a1)            \
      for (int a2 = 0; a2 < 2; ++a2)          \
        for (int a3 = 0; a3 < 4; ++a3)        \
          for (int a4 = 0; a4 < 2; ++a4) acc[a1][a2][a3][a4] = z; \
  }

#define EPI_BASES()                                             \
  const int lane = threadIdx.x & 63;                            \
  const int wave = threadIdx.x >> 6;                            \
  const int wm = wave >> 2, wn = wave & 3;                      \
  const int rb = wm * 128 + ((lane >> 4) << 2);                 \
  const int cb = wn * 64 + (lane & 15);

// ---------------- QKV projection ----------------------------------------------
__global__ __launch_bounds__(512, 2) void qkv_kernel(const bf16* __restrict__ xb,
                                                     const bf16* __restrict__ Wq,
                                                     const bf16* __restrict__ Wk,
                                                     const bf16* __restrict__ Wv,
                                                     bf16* __restrict__ Q,
                                                     bf16* __restrict__ K,
                                                     bf16* __restrict__ Vt) {
  extern __shared__ char lds[];
  const int l = xcd_swz(blockIdx.x, 192);
  const int z = l >> 6, tt = l & 63, bi = tt >> 2, bj = tt & 3;
  const bf16* W = (z == 0) ? Wq : (z == 1) ? Wk : Wv;
  ACC256_INIT();
  gemm256_core(xb, W, DIN, DIN, bi * 256, bj * 256, 0, 16, acc, lds);
  EPI_BASES();
  const int rbase = bi * 256 + rb, cbase = bj * 256 + cb;
  if (z < 2) {
    bf16* O = (z == 0) ? Q : K;
#pragma unroll
    for (int mh = 0; mh < 2; ++mh)
#pragma unroll
      for (int nh = 0; nh < 2; ++nh)
#pragma unroll
        for (int mt = 0; mt < 4; ++mt)
#pragma unroll
          for (int nt = 0; nt < 2; ++nt)
#pragma unroll
            for (int j = 0; j < 4; ++j)
              O[(size_t)(rbase + mh * 64 + mt * 16 + j) * DOUT + (cbase + nh * 32 + nt * 16)] =
                  (bf16)acc[mh][nh][mt][nt][j];
  } else {
#pragma unroll
    for (int mh = 0; mh < 2; ++mh)
#pragma unroll
      for (int nh = 0; nh < 2; ++nh)
#pragma unroll
        for (int mt = 0; mt < 4; ++mt)
#pragma unroll
          for (int nt = 0; nt < 2; ++nt)
#pragma unroll
            for (int j = 0; j < 4; ++j)
              Vt[(size_t)(cbase + nh * 32 + nt * 16) * SEQ + (rbase + mh * 64 + mt * 16 + j)] =
                  (bf16)acc[mh][nh][mt][nt][j];
  }
}

// ---------------- scores = Q K^T * scale, triangular 256-grid ------------------
__global__ __launch_bounds__(512, 2) void scores_kernel(const bf16* __restrict__ Q,
                                                        const bf16* __restrict__ Km,
                                                        float* __restrict__ Sc) {
  extern __shared__ char lds[];
  const int t = xcd_swz(blockIdx.x, 136);
  int bi = (int)((sqrtf(8.0f * (float)t + 1.0f) - 1.0f) * 0.5f);
  while ((bi + 1) * (bi + 2) / 2 <= t) ++bi;
  while (bi * (bi + 1) / 2 > t) --bi;
  const int bj = t - bi * (bi + 1) / 2;
  ACC256_INIT();
  gemm256_core(Q, Km, DOUT, DOUT, bi * 256, bj * 256, 0, 16, acc, lds);
  EPI_BASES();
  const int rbase = bi * 256 + rb, cbase = bj * 256 + cb;
  const float scale = 0.03125f;  // 1/sqrt(1024)
#pragma unroll
  for (int mh = 0; mh < 2; ++mh)
#pragma unroll
    for (int nh = 0; nh < 2; ++nh)
#pragma unroll
      for (int mt = 0; mt < 4; ++mt)
#pragma unroll
        for (int nt = 0; nt < 2; ++nt)
#pragma unroll
          for (int j = 0; j < 4; ++j)
            Sc[(size_t)(rbase + mh * 64 + mt * 16 + j) * SEQ + (cbase + nh * 32 + nt * 16)] =
                acc[mh][nh][mt][nt][j] * scale;
}

// ---------------- row softmax (vectorized): zero-pad to 256-col boundary ------
__global__ __launch_bounds__(256) void softmax_kernel(const float* __restrict__ Sc,
                                                      bf16* __restrict__ P) {
  __shared__ float rowbuf[SEQ];
  __shared__ float red[8];
  const int r = blockIdx.x;
  const int n = r + 1;
  const int nw4 = ((r >> 8) + 1) << 6;  // padded row length / 4 (256-col blocks)
  const int tid = threadIdx.x;
  const float* src = Sc + (size_t)r * SEQ;
  const float NEG = -__builtin_inff();

  float lmax = NEG;
  for (int g = tid; g < nw4; g += 256) {
    float4 v = reinterpret_cast<const float4*>(src)[g];
    const int b = g * 4;
    v.x = (b + 0 < n) ? v.x : NEG;
    v.y = (b + 1 < n) ? v.y : NEG;
    v.z = (b + 2 < n) ? v.z : NEG;
    v.w = (b + 3 < n) ? v.w : NEG;
    reinterpret_cast<float4*>(rowbuf)[g] = v;
    lmax = fmaxf(fmaxf(lmax, fmaxf(v.x, v.y)), fmaxf(v.z, v.w));
  }
#pragma unroll
  for (int m = 32; m >= 1; m >>= 1) lmax = fmaxf(lmax, __shfl_xor(lmax, m, 64));
  if ((tid & 63) == 0) red[tid >> 6] = lmax;
  __syncthreads();
  const float rmax = fmaxf(fmaxf(red[0], red[1]), fmaxf(red[2], red[3]));

  float lsum = 0.f;
  for (int g = tid; g < nw4; g += 256) {
    float4 v = reinterpret_cast<const float4*>(rowbuf)[g];
    v.x = __expf(v.x - rmax);
    v.y = __expf(v.y - rmax);
    v.z = __expf(v.z - rmax);
    v.w = __expf(v.w - rmax);
    reinterpret_cast<float4*>(rowbuf)[g] = v;
    lsum += v.x + v.y + v.z + v.w;
  }
#pragma unroll
  for (int m = 32; m >= 1; m >>= 1) lsum += __shfl_xor(lsum, m, 64);
  if ((tid & 63) == 0) red[4 + (tid >> 6)] = lsum;
  __syncthreads();
  const float inv = 1.0f / (red[4] + red[5] + red[6] + red[7]);

  bf16* dst = P + (size_t)r * SEQ;
  for (int g = tid; g < nw4; g += 256) {
    float4 v = reinterpret_cast<const float4*>(rowbuf)[g];
    bf16x4v o;
    o[0] = (bf16)(v.x * inv);
    o[1] = (bf16)(v.y * inv);
    o[2] = (bf16)(v.z * inv);
    o[3] = (bf16)(v.w * inv);
    *reinterpret_cast<bf16x4v*>(dst + g * 4) = o;
  }
}

// ---------------- out += P @ V (uniform split-K, atomic accumulate) -----------
// grid 288 = 72 chunk-slots x 4 bj (bj inner), XCD-swizzled.
// Per bi: Ti=(bi+1)*4 K-tiles, nch=ceil((bi+1)/2) chunks, balanced (<=8 tiles).
__global__ __launch_bounds__(512, 2) void pv_kernel(const bf16* __restrict__ P,
                                                    const bf16* __restrict__ Vt,
                                                    float* __restrict__ Out) {
  extern __shared__ char lds[];
  const int l = xcd_swz(blockIdx.x, 288);
  const int bj = l & 3;
  int c = l >> 2, bi = 0;
  for (;;) {
    const int nch = (bi + 2) >> 1;  // ceil((bi+1)/2)
    if (c < nch) break;
    c -= nch; ++bi;
  }
  const int nch = (bi + 2) >> 1;
  const int Ti = (bi + 1) * 4;
  const int base = Ti / nch, rem = Ti % nch;
  const int kt0 = c * base + imin(c, rem);
  const int ktn = base + (c < rem ? 1 : 0);
  ACC256_INIT();
  gemm256_core(P, Vt, SEQ, SEQ, bi * 256, bj * 256, kt0, ktn, acc, lds);
  EPI_BASES();
  const int rbase = bi * 256 + rb, cbase = bj * 256 + cb;
  if (nch == 1) {
#pragma unroll
    for (int mh = 0; mh < 2; ++mh)
#pragma unroll
      for (int nh = 0; nh < 2; ++nh)
#pragma unroll
        for (int mt = 0; mt < 4; ++mt)
#pragma unroll
          for (int nt = 0; nt < 2; ++nt)
#pragma unroll
            for (int j = 0; j < 4; ++j)
              Out[(size_t)(rbase + mh * 64 + mt * 16 + j) * DOUT + (cbase + nh * 32 + nt * 16)] =
                  acc[mh][nh][mt][nt][j];
  } else {
#pragma unroll
    for (int mh = 0; mh < 2; ++mh)
#pragma unroll
      for (int nh = 0; nh < 2; ++nh)
#pragma unroll
        for (int mt = 0; mt < 4; ++mt)
#pragma unroll
          for (int nt = 0; nt < 2; ++nt)
#pragma unroll
            for (int j = 0; j < 4; ++j)
              atomicAdd(&Out[(size_t)(rbase + mh * 64 + mt * 16 + j) * DOUT + (cbase + nh * 32 + nt * 16)],
                        acc[mh][nh][mt][nt][j]);
  }
}

extern "C" void kernel_launch(void* const* d_in, const int* in_sizes, int n_in,
                              void* d_out, int out_size, void* d_ws, size_t ws_size,
                              hipStream_t stream) {
  const float* x  = (const float*)d_in[0];
  const float* Wq = (const float*)d_in[1];
  const float* Wk = (const float*)d_in[2];
  const float* Wv = (const float*)d_in[3];
  float* Out = (float*)d_out;

  char* base = (char*)d_ws;
  bf16* xb  = (bf16*)(base + 0);          //  8 MB  [4096x1024]
  bf16* wqb = (bf16*)(base + 8388608);    //  2 MB
  bf16* wkb = (bf16*)(base + 10485760);   //  2 MB
  bf16* wvb = (bf16*)(base + 12582912);   //  2 MB
  bf16* Qb  = (bf16*)(base + 14680064);   //  8 MB
  bf16* Kb  = (bf16*)(base + 23068672);   //  8 MB
  bf16* Vtb = (bf16*)(base + 31457280);   //  8 MB  [1024x4096] transposed
  float* Sc = (float*)(base + 39845888);  // 64 MB  [4096x4096] fp32
  bf16* P   = (bf16*)(base + 106954752);  // 32 MB  [4096x4096] bf16

  (void)hipFuncSetAttribute((const void*)qkv_kernel,
                            hipFuncAttributeMaxDynamicSharedMemorySize, 131072);
  (void)hipFuncSetAttribute((const void*)scores_kernel,
                            hipFuncAttributeMaxDynamicSharedMemorySize, 131072);
  (void)hipFuncSetAttribute((const void*)pv_kernel,
                            hipFuncAttributeMaxDynamicSharedMemorySize, 131072);

  hipMemsetAsync(d_out, 0, (size_t)out_size * sizeof(float), stream);

  cast_all_kernel<<<7168, 256, 0, stream>>>(x, Wq, Wk, Wv, xb, wqb, wkb, wvb);

  qkv_kernel<<<192, 512, 131072, stream>>>(xb, wqb, wkb, wvb, Qb, Kb, Vtb);
  scores_kernel<<<136, 512, 131072, stream>>>(Qb, Kb, Sc);
  softmax_kernel<<<SEQ, 256, 0, stream>>>(Sc, P);
  pv_kernel<<<288, 512, 131072, stream>>>(P, Vtb, Out);
}

// Round 8
// 151.735 us; speedup vs baseline: 1.1149x; 1.1149x over previous
//
#include <hip/hip_runtime.h>
#include <hip/hip_bf16.h>
#include <stdint.h>

#define SEQ 4096
#define DIN 1024
#define DOUT 1024

typedef __bf16 bf16;
typedef __bf16 bf16x4v __attribute__((ext_vector_type(4)));
typedef __bf16 bf16x8v __attribute__((ext_vector_type(8)));
typedef float f32x4 __attribute__((ext_vector_type(4)));

#define AS1 __attribute__((address_space(1)))
#define AS3 __attribute__((address_space(3)))

__device__ __forceinline__ void load_lds16(const void* g, void* l) {
  __builtin_amdgcn_global_load_lds((const AS1 uint32_t*)g, (AS3 uint32_t*)l, 16, 0, 0);
}
__device__ __forceinline__ int imin(int a, int b) { return a < b ? a : b; }

// m204 bijective XCD swizzle
__device__ __forceinline__ int xcd_swz(int orig, int nwg) {
  const int q = nwg >> 3, r = nwg & 7;
  const int x = orig & 7, idx = orig >> 3;
  return (x < r ? x * (q + 1) : r * (q + 1) + (x - r) * q) + idx;
}

// ---------------- fused cast fp32 -> bf16 for x, Wq, Wk, Wv (exact 1D grid) ---
__global__ __launch_bounds__(256) void cast_all_kernel(
    const float* __restrict__ x, const float* __restrict__ wq,
    const float* __restrict__ wk, const float* __restrict__ wv,
    bf16* __restrict__ xb, bf16* __restrict__ wqb,
    bf16* __restrict__ wkb, bf16* __restrict__ wvb) {
  const int id = blockIdx.x;
  const float* in; bf16* out; int blk;
  if (id < 4096) {
    in = x; out = xb; blk = id;
  } else {
    const int w = (id - 4096) >> 10;
    blk = (id - 4096) & 1023;
    in = (w == 0) ? wq : (w == 1) ? wk : wv;
    out = (w == 0) ? wqb : (w == 1) ? wkb : wvb;
  }
  const int i = (blk * 256 + threadIdx.x) * 4;
  float4 v = *reinterpret_cast<const float4*>(in + i);
  bf16x4v o;
  o[0] = (bf16)v.x; o[1] = (bf16)v.y; o[2] = (bf16)v.z; o[3] = (bf16)v.w;
  *reinterpret_cast<bf16x4v*>(out + i) = o;
}

// =============== 256x256 BT-GEMM core, BK=64, 8 waves, 128KB LDS (R5) =========
// C[256x256] += A[brow..][k] * B[bcol..][k]^T, k in K-tiles [kt0, kt0+ktn) of 64.
// 512 threads = 8 waves (2M x 4N); wave output 128x64 = acc[2][2][4][2] f32x4.
// LDS (bytes): dbuf*65536 + {A0:0, A1:16384, B0:32768, B1:49152}; each half-tile
// 128 rows x 128B, XOR-swizzled: slot(r,c) holds global (r, c ^ ((r&7)<<4)).
// Stage keeps LDS dest LINEAR (global_load_lds requirement), swizzles the global
// SOURCE column; read side applies the same XOR (involution). Verified: 0 bank
// conflicts (R5 counters).
struct G256 {
  const char *pa, *pb;
  size_t lda2, ldb2;
  char* lds;
  int tid;
};

__device__ __forceinline__ void stage_tile(const G256& g, int sd, int kt) {
  const size_t kb = (size_t)kt * 128;
  char* d = g.lds + sd * 65536;
  const int to = g.tid * 16;
  load_lds16(g.pa + kb,                  d + 0     + to);  // A0 rows 0-63
  load_lds16(g.pa + kb + 64  * g.lda2,   d + 8192  + to);  // A0 rows 64-127
  load_lds16(g.pb + kb,                  d + 32768 + to);  // B0 rows 0-63
  load_lds16(g.pb + kb + 64  * g.ldb2,   d + 40960 + to);  // B0 rows 64-127
  load_lds16(g.pb + kb + 128 * g.ldb2,   d + 49152 + to);  // B1 rows 0-63
  load_lds16(g.pb + kb + 192 * g.ldb2,   d + 57344 + to);  // B1 rows 64-127
  load_lds16(g.pa + kb + 128 * g.lda2,   d + 16384 + to);  // A1 rows 0-63
  load_lds16(g.pa + kb + 192 * g.lda2,   d + 24576 + to);  // A1 rows 64-127
}

__device__ __forceinline__ void gemm256_core(const bf16* __restrict__ A,
                                             const bf16* __restrict__ B,
                                             int lda, int ldb, int brow, int bcol,
                                             int kt0, int ktn,
                                             f32x4 acc[2][2][4][2], char* lds) {
  const int tid = threadIdx.x;
  const int sr = tid >> 3;                              // staging row 0..63
  const int cs = ((tid & 7) << 4) ^ ((sr & 7) << 4);    // swizzled src byte col
  G256 g;
  g.lda2 = (size_t)lda * 2; g.ldb2 = (size_t)ldb * 2;
  g.pa = (const char*)A + (size_t)(brow + sr) * g.lda2 + cs;
  g.pb = (const char*)B + (size_t)(bcol + sr) * g.ldb2 + cs;
  g.lds = lds; g.tid = tid;

  const int lane = tid & 63, lrow = lane & 15, lkg = lane >> 4;
  const int wave = tid >> 6, wm = wave >> 2, wn = wave & 3;
  const int aReg = wm * 16384;                 // this wave's A half-tile
  const int bReg = 32768 + (wn >> 1) * 16384;  // this wave's B half-tile
  const int brow0 = (wn & 1) * 64;             // row base within B half
  const int swz = (lrow & 7) << 4;

  // prologue: stage K-tile 0, drain, barrier
  stage_tile(g, 0, kt0);
  asm volatile("s_waitcnt vmcnt(0)" ::: "memory");
  __builtin_amdgcn_s_barrier();
  __builtin_amdgcn_sched_barrier(0);

  for (int t = 0; t < ktn; ++t) {
    const int d = t & 1;
    // stage next K-tile (clamped dup on last iter; lands in unread dbuf)
    stage_tile(g, d ^ 1, kt0 + imin(t + 1, ktn - 1));
    const char* db = lds + d * 65536;

    bf16x8v a[4][2], b0[2][2], b1[2][2];
#pragma unroll
    for (int nt = 0; nt < 2; ++nt)
#pragma unroll
      for (int ks = 0; ks < 2; ++ks) {
        const int ck = (ks * 64 + lkg * 16) ^ swz;
        b0[nt][ks] = *(const bf16x8v*)(db + bReg + (brow0 + nt * 16 + lrow) * 128 + ck);
        b1[nt][ks] = *(const bf16x8v*)(db + bReg + (brow0 + 32 + nt * 16 + lrow) * 128 + ck);
      }
    // ---- mh = 0 (wave rows 0-63) ----
#pragma unroll
    for (int mt = 0; mt < 4; ++mt)
#pragma unroll
      for (int ks = 0; ks < 2; ++ks)
        a[mt][ks] = *(const bf16x8v*)(db + aReg + (mt * 16 + lrow) * 128 + ((ks * 64 + lkg * 16) ^ swz));
    __builtin_amdgcn_s_setprio(1);
#pragma unroll
    for (int mt = 0; mt < 4; ++mt)
#pragma unroll
      for (int nt = 0; nt < 2; ++nt)
#pragma unroll
        for (int ks = 0; ks < 2; ++ks) {
          acc[0][0][mt][nt] = __builtin_amdgcn_mfma_f32_16x16x32_bf16(a[mt][ks], b0[nt][ks], acc[0][0][mt][nt], 0, 0, 0);
          acc[0][1][mt][nt] = __builtin_amdgcn_mfma_f32_16x16x32_bf16(a[mt][ks], b1[nt][ks], acc[0][1][mt][nt], 0, 0, 0);
        }
    __builtin_amdgcn_s_setprio(0);
    // ---- mh = 1 (wave rows 64-127) ----
#pragma unroll
    for (int mt = 0; mt < 4; ++mt)
#pragma unroll
      for (int ks = 0; ks < 2; ++ks)
        a[mt][ks] = *(const bf16x8v*)(db + aReg + ((64 + mt * 16 + lrow) * 128) + ((ks * 64 + lkg * 16) ^ swz));
    __builtin_amdgcn_s_setprio(1);
#pragma unroll
    for (int mt = 0; mt < 4; ++mt)
#pragma unroll
      for (int nt = 0; nt < 2; ++nt)
#pragma unroll
        for (int ks = 0; ks < 2; ++ks) {
          acc[1][1][mt][nt] = __builtin_amdgcn_mfma_f32_16x16x32_bf16(a[mt][ks], b1[nt][ks], acc[1][1][mt][nt], 0, 0, 0);
          acc[1][0][mt][nt] = __builtin_amdgcn_mfma_f32_16x16x32_bf16(a[mt][ks], b0[nt][ks], acc[1][0][mt][nt], 0, 0, 0);
        }
    __builtin_amdgcn_s_setprio(0);
    // boundary: next tile fully landed + all waves done reading this dbuf
    asm volatile("s_waitcnt vmcnt(0)" ::: "memory");
    __builtin_amdgcn_s_barrier();
    __builtin_amdgcn_sched_barrier(0);
  }
}

#define ACC256_INIT()                         \
  f32x4 acc[2][2][4][2];                      \
  {                                           \
    f32x4 z = {0.f, 0.f, 0.f, 0.f};           \
    for (int a1 = 0; a1 < 2; ++a1)            \
      for (int a2 = 0; a2 < 2; ++a2)          \
        for (int a3 = 0; a3 < 4; ++a3)        \
          for (int a4 = 0; a4 < 2; ++a4) acc[a1][a2][a3][a4] = z; \
  }

#define EPI_BASES()                                             \
  const int lane = threadIdx.x & 63;                            \
  const int wave = threadIdx.x >> 6;                            \
  const int wm = wave >> 2, wn = wave & 3;                      \
  const int rb = wm * 128 + ((lane >> 4) << 2);                 \
  const int cb = wn * 64 + (lane & 15);

// ---------------- QK projection: Q,K row-major bf16 ---------------------------
// grid 128 = 2z x 16bi x 4bj (bj inner), XCD-swizzled. K-tiles: 16.
__global__ __launch_bounds__(512, 2) void qk_kernel(const bf16* __restrict__ xb,
                                                    const bf16* __restrict__ Wq,
                                                    const bf16* __restrict__ Wk,
                                                    bf16* __restrict__ Q,
                                                    bf16* __restrict__ K) {
  extern __shared__ char lds[];
  const int l = xcd_swz(blockIdx.x, 128);
  const int z = l >> 6, tt = l & 63, bi = tt >> 2, bj = tt & 3;
  const bf16* W = (z == 0) ? Wq : Wk;
  ACC256_INIT();
  gemm256_core(xb, W, DIN, DIN, bi * 256, bj * 256, 0, 16, acc, lds);
  EPI_BASES();
  const int rbase = bi * 256 + rb, cbase = bj * 256 + cb;
  bf16* O = (z == 0) ? Q : K;
#pragma unroll
  for (int mh = 0; mh < 2; ++mh)
#pragma unroll
    for (int nh = 0; nh < 2; ++nh)
#pragma unroll
      for (int mt = 0; mt < 4; ++mt)
#pragma unroll
        for (int nt = 0; nt < 2; ++nt)
#pragma unroll
          for (int j = 0; j < 4; ++j)
            O[(size_t)(rbase + mh * 64 + mt * 16 + j) * DOUT + (cbase + nh * 32 + nt * 16)] =
                (bf16)acc[mh][nh][mt][nt][j];
}

// ---------------- scores (136 tri blocks) + V-projection (64 blocks) ----------
// grid 200, XCD-swizzled. Both classes co-resident: V-proj overlaps scores.
__global__ __launch_bounds__(512, 2) void scores_v_kernel(const bf16* __restrict__ Q,
                                                          const bf16* __restrict__ Km,
                                                          float* __restrict__ Sc,
                                                          const bf16* __restrict__ xb,
                                                          const bf16* __restrict__ Wv,
                                                          bf16* __restrict__ Vt) {
  extern __shared__ char lds[];
  const int l = xcd_swz(blockIdx.x, 200);
  if (l < 64) {
    // ---- V projection: out written transposed into Vt [1024][4096] ----
    const int bi = l >> 2, bj = l & 3;
    ACC256_INIT();
    gemm256_core(xb, Wv, DIN, DIN, bi * 256, bj * 256, 0, 16, acc, lds);
    EPI_BASES();
    const int rbase = bi * 256 + rb, cbase = bj * 256 + cb;
#pragma unroll
    for (int mh = 0; mh < 2; ++mh)
#pragma unroll
      for (int nh = 0; nh < 2; ++nh)
#pragma unroll
        for (int mt = 0; mt < 4; ++mt)
#pragma unroll
          for (int nt = 0; nt < 2; ++nt)
#pragma unroll
            for (int j = 0; j < 4; ++j)
              Vt[(size_t)(cbase + nh * 32 + nt * 16) * SEQ + (rbase + mh * 64 + mt * 16 + j)] =
                  (bf16)acc[mh][nh][mt][nt][j];
  } else {
    // ---- scores tile (triangular) ----
    const int t = l - 64;
    int bi = (int)((sqrtf(8.0f * (float)t + 1.0f) - 1.0f) * 0.5f);
    while ((bi + 1) * (bi + 2) / 2 <= t) ++bi;
    while (bi * (bi + 1) / 2 > t) --bi;
    const int bj = t - bi * (bi + 1) / 2;
    ACC256_INIT();
    gemm256_core(Q, Km, DOUT, DOUT, bi * 256, bj * 256, 0, 16, acc, lds);
    EPI_BASES();
    const int rbase = bi * 256 + rb, cbase = bj * 256 + cb;
    const float scale = 0.03125f;  // 1/sqrt(1024)
#pragma unroll
    for (int mh = 0; mh < 2; ++mh)
#pragma unroll
      for (int nh = 0; nh < 2; ++nh)
#pragma unroll
        for (int mt = 0; mt < 4; ++mt)
#pragma unroll
          for (int nt = 0; nt < 2; ++nt)
#pragma unroll
            for (int j = 0; j < 4; ++j)
              Sc[(size_t)(rbase + mh * 64 + mt * 16 + j) * SEQ + (cbase + nh * 32 + nt * 16)] =
                  acc[mh][nh][mt][nt][j] * scale;
  }
}

// ---------------- row softmax (vectorized): zero-pad to 256-col boundary ------
__global__ __launch_bounds__(256) void softmax_kernel(const float* __restrict__ Sc,
                                                      bf16* __restrict__ P) {
  __shared__ float rowbuf[SEQ];
  __shared__ float red[8];
  const int r = blockIdx.x;
  const int n = r + 1;
  const int nw4 = ((r >> 8) + 1) << 6;  // padded row length / 4 (256-col blocks)
  const int tid = threadIdx.x;
  const float* src = Sc + (size_t)r * SEQ;
  const float NEG = -__builtin_inff();

  float lmax = NEG;
  for (int g = tid; g < nw4; g += 256) {
    float4 v = reinterpret_cast<const float4*>(src)[g];
    const int b = g * 4;
    v.x = (b + 0 < n) ? v.x : NEG;
    v.y = (b + 1 < n) ? v.y : NEG;
    v.z = (b + 2 < n) ? v.z : NEG;
    v.w = (b + 3 < n) ? v.w : NEG;
    reinterpret_cast<float4*>(rowbuf)[g] = v;
    lmax = fmaxf(fmaxf(lmax, fmaxf(v.x, v.y)), fmaxf(v.z, v.w));
  }
#pragma unroll
  for (int m = 32; m >= 1; m >>= 1) lmax = fmaxf(lmax, __shfl_xor(lmax, m, 64));
  if ((tid & 63) == 0) red[tid >> 6] = lmax;
  __syncthreads();
  const float rmax = fmaxf(fmaxf(red[0], red[1]), fmaxf(red[2], red[3]));

  float lsum = 0.f;
  for (int g = tid; g < nw4; g += 256) {
    float4 v = reinterpret_cast<const float4*>(rowbuf)[g];
    v.x = __expf(v.x - rmax);
    v.y = __expf(v.y - rmax);
    v.z = __expf(v.z - rmax);
    v.w = __expf(v.w - rmax);
    reinterpret_cast<float4*>(rowbuf)[g] = v;
    lsum += v.x + v.y + v.z + v.w;
  }
#pragma unroll
  for (int m = 32; m >= 1; m >>= 1) lsum += __shfl_xor(lsum, m, 64);
  if ((tid & 63) == 0) red[4 + (tid >> 6)] = lsum;
  __syncthreads();
  const float inv = 1.0f / (red[4] + red[5] + red[6] + red[7]);

  bf16* dst = P + (size_t)r * SEQ;
  for (int g = tid; g < nw4; g += 256) {
    float4 v = reinterpret_cast<const float4*>(rowbuf)[g];
    bf16x4v o;
    o[0] = (bf16)(v.x * inv);
    o[1] = (bf16)(v.y * inv);
    o[2] = (bf16)(v.z * inv);
    o[3] = (bf16)(v.w * inv);
    *reinterpret_cast<bf16x4v*>(dst + g * 4) = o;
  }
}

// ---------------- out += P @ V (balanced split-K <= 10 tiles, grid 244) -------
// Per bi: Ti=(bi+1)*4 K-tiles, nch=ceil(Ti/10); 61 slots x 4 bj = 244 <= 256.
// Odd chunks store fragments in reversed order to de-contend the atomics.
__global__ __launch_bounds__(512, 2) void pv_kernel(const bf16* __restrict__ P,
                                                    const bf16* __restrict__ Vt,
                                                    float* __restrict__ Out) {
  extern __shared__ char lds[];
  const int l = xcd_swz(blockIdx.x, 244);
  const int bj = l & 3;
  int c = l >> 2, bi = 0;
  for (;;) {
    const int nch = (4 * (bi + 1) + 9) / 10;
    if (c < nch) break;
    c -= nch; ++bi;
  }
  const int nch = (4 * (bi + 1) + 9) / 10;
  const int Ti = (bi + 1) * 4;
  const int base = Ti / nch, rem = Ti % nch;
  const int kt0 = c * base + imin(c, rem);
  const int ktn = base + (c < rem ? 1 : 0);
  ACC256_INIT();
  gemm256_core(P, Vt, SEQ, SEQ, bi * 256, bj * 256, kt0, ktn, acc, lds);
  EPI_BASES();
  const int rbase = bi * 256 + rb, cbase = bj * 256 + cb;
  if (nch == 1) {
#pragma unroll
    for (int mh = 0; mh < 2; ++mh)
#pragma unroll
      for (int nh = 0; nh < 2; ++nh)
#pragma unroll
        for (int mt = 0; mt < 4; ++mt)
#pragma unroll
          for (int nt = 0; nt < 2; ++nt)
#pragma unroll
            for (int j = 0; j < 4; ++j)
              Out[(size_t)(rbase + mh * 64 + mt * 16 + j) * DOUT + (cbase + nh * 32 + nt * 16)] =
                  acc[mh][nh][mt][nt][j];
  } else if ((c & 1) == 0) {
#pragma unroll
    for (int mh = 0; mh < 2; ++mh)
#pragma unroll
      for (int nh = 0; nh < 2; ++nh)
#pragma unroll
        for (int mt = 0; mt < 4; ++mt)
#pragma unroll
          for (int nt = 0; nt < 2; ++nt)
#pragma unroll
            for (int j = 0; j < 4; ++j)
              atomicAdd(&Out[(size_t)(rbase + mh * 64 + mt * 16 + j) * DOUT + (cbase + nh * 32 + nt * 16)],
                        acc[mh][nh][mt][nt][j]);
  } else {
#pragma unroll
    for (int mh = 1; mh >= 0; --mh)
#pragma unroll
      for (int nh = 1; nh >= 0; --nh)
#pragma unroll
        for (int mt = 3; mt >= 0; --mt)
#pragma unroll
          for (int nt = 1; nt >= 0; --nt)
#pragma unroll
            for (int j = 0; j < 4; ++j)
              atomicAdd(&Out[(size_t)(rbase + mh * 64 + mt * 16 + j) * DOUT + (cbase + nh * 32 + nt * 16)],
                        acc[mh][nh][mt][nt][j]);
  }
}

extern "C" void kernel_launch(void* const* d_in, const int* in_sizes, int n_in,
                              void* d_out, int out_size, void* d_ws, size_t ws_size,
                              hipStream_t stream) {
  const float* x  = (const float*)d_in[0];
  const float* Wq = (const float*)d_in[1];
  const float* Wk = (const float*)d_in[2];
  const float* Wv = (const float*)d_in[3];
  float* Out = (float*)d_out;

  char* base = (char*)d_ws;
  bf16* xb  = (bf16*)(base + 0);          //  8 MB  [4096x1024]
  bf16* wqb = (bf16*)(base + 8388608);    //  2 MB
  bf16* wkb = (bf16*)(base + 10485760);   //  2 MB
  bf16* wvb = (bf16*)(base + 12582912);   //  2 MB
  bf16* Qb  = (bf16*)(base + 14680064);   //  8 MB
  bf16* Kb  = (bf16*)(base + 23068672);   //  8 MB
  bf16* Vtb = (bf16*)(base + 31457280);   //  8 MB  [1024x4096] transposed
  float* Sc = (float*)(base + 39845888);  // 64 MB  [4096x4096] fp32
  bf16* P   = (bf16*)(base + 106954752);  // 32 MB  [4096x4096] bf16

  (void)hipFuncSetAttribute((const void*)qk_kernel,
                            hipFuncAttributeMaxDynamicSharedMemorySize, 131072);
  (void)hipFuncSetAttribute((const void*)scores_v_kernel,
                            hipFuncAttributeMaxDynamicSharedMemorySize, 131072);
  (void)hipFuncSetAttribute((const void*)pv_kernel,
                            hipFuncAttributeMaxDynamicSharedMemorySize, 131072);

  hipMemsetAsync(d_out, 0, (size_t)out_size * sizeof(float), stream);

  cast_all_kernel<<<7168, 256, 0, stream>>>(x, Wq, Wk, Wv, xb, wqb, wkb, wvb);

  qk_kernel<<<128, 512, 131072, stream>>>(xb, wqb, wkb, Qb, Kb);
  scores_v_kernel<<<200, 512, 131072, stream>>>(Qb, Kb, Sc, xb, wvb, Vtb);
  softmax_kernel<<<SEQ, 256, 0, stream>>>(Sc, P);
  pv_kernel<<<244, 512, 131072, stream>>>(P, Vtb, Out);
}

// Round 9
// 121.794 us; speedup vs baseline: 1.3890x; 1.2458x over previous
//
#include <hip/hip_runtime.h>
#include <hip/hip_bf16.h>
#include <stdint.h>

#define SEQ 4096
#define DIN 1024
#define DOUT 1024

typedef __bf16 bf16;
typedef __bf16 bf16x4v __attribute__((ext_vector_type(4)));
typedef __bf16 bf16x8v __attribute__((ext_vector_type(8)));
typedef float f32x4 __attribute__((ext_vector_type(4)));

#define AS1 __attribute__((address_space(1)))
#define AS3 __attribute__((address_space(3)))

__device__ __forceinline__ void load_lds16(const void* g, void* l) {
  __builtin_amdgcn_global_load_lds((const AS1 uint32_t*)g, (AS3 uint32_t*)l, 16, 0, 0);
}
__device__ __forceinline__ int imin(int a, int b) { return a < b ? a : b; }

// m204 bijective XCD swizzle
__device__ __forceinline__ int xcd_swz(int orig, int nwg) {
  const int q = nwg >> 3, r = nwg & 7;
  const int x = orig & 7, idx = orig >> 3;
  return (x < r ? x * (q + 1) : r * (q + 1) + (x - r) * q) + idx;
}

// ---------------- fused cast fp32 -> bf16 for x, Wq, Wk, Wv (exact 1D grid) ---
__global__ __launch_bounds__(256) void cast_all_kernel(
    const float* __restrict__ x, const float* __restrict__ wq,
    const float* __restrict__ wk, const float* __restrict__ wv,
    bf16* __restrict__ xb, bf16* __restrict__ wqb,
    bf16* __restrict__ wkb, bf16* __restrict__ wvb) {
  const int id = blockIdx.x;
  const float* in; bf16* out; int blk;
  if (id < 4096) {
    in = x; out = xb; blk = id;
  } else {
    const int w = (id - 4096) >> 10;
    blk = (id - 4096) & 1023;
    in = (w == 0) ? wq : (w == 1) ? wk : wv;
    out = (w == 0) ? wqb : (w == 1) ? wkb : wvb;
  }
  const int i = (blk * 256 + threadIdx.x) * 4;
  float4 v = *reinterpret_cast<const float4*>(in + i);
  bf16x4v o;
  o[0] = (bf16)v.x; o[1] = (bf16)v.y; o[2] = (bf16)v.z; o[3] = (bf16)v.w;
  *reinterpret_cast<bf16x4v*>(out + i) = o;
}

// =============== 256x256 BT-GEMM core, BK=64, 8 waves, 128KB LDS (R5) =========
// C[256x256] += A[brow..][k] * B[bcol..][k]^T, k in K-tiles [kt0, kt0+ktn) of 64.
// 512 threads = 8 waves (2M x 4N); wave output 128x64 = acc[2][2][4][2] f32x4.
// LDS (bytes): dbuf*65536 + {A0:0, A1:16384, B0:32768, B1:49152}; each half-tile
// 128 rows x 128B, XOR-swizzled: slot(r,c) holds global (r, c ^ ((r&7)<<4)).
// Stage keeps LDS dest LINEAR (global_load_lds requirement), swizzles the global
// SOURCE column; read side applies the same XOR (involution). 0 bank conflicts
// (verified R5/R7 counters).
struct G256 {
  const char *pa, *pb;
  size_t lda2, ldb2;
  char* lds;
  int tid;
};

__device__ __forceinline__ void stage_tile(const G256& g, int sd, int kt) {
  const size_t kb = (size_t)kt * 128;
  char* d = g.lds + sd * 65536;
  const int to = g.tid * 16;
  load_lds16(g.pa + kb,                  d + 0     + to);  // A0 rows 0-63
  load_lds16(g.pa + kb + 64  * g.lda2,   d + 8192  + to);  // A0 rows 64-127
  load_lds16(g.pb + kb,                  d + 32768 + to);  // B0 rows 0-63
  load_lds16(g.pb + kb + 64  * g.ldb2,   d + 40960 + to);  // B0 rows 64-127
  load_lds16(g.pb + kb + 128 * g.ldb2,   d + 49152 + to);  // B1 rows 0-63
  load_lds16(g.pb + kb + 192 * g.ldb2,   d + 57344 + to);  // B1 rows 64-127
  load_lds16(g.pa + kb + 128 * g.lda2,   d + 16384 + to);  // A1 rows 0-63
  load_lds16(g.pa + kb + 192 * g.lda2,   d + 24576 + to);  // A1 rows 64-127
}

__device__ __forceinline__ void gemm256_core(const bf16* __restrict__ A,
                                             const bf16* __restrict__ B,
                                             int lda, int ldb, int brow, int bcol,
                                             int kt0, int ktn,
                                             f32x4 acc[2][2][4][2], char* lds) {
  const int tid = threadIdx.x;
  const int sr = tid >> 3;                              // staging row 0..63
  const int cs = ((tid & 7) << 4) ^ ((sr & 7) << 4);    // swizzled src byte col
  G256 g;
  g.lda2 = (size_t)lda * 2; g.ldb2 = (size_t)ldb * 2;
  g.pa = (const char*)A + (size_t)(brow + sr) * g.lda2 + cs;
  g.pb = (const char*)B + (size_t)(bcol + sr) * g.ldb2 + cs;
  g.lds = lds; g.tid = tid;

  const int lane = tid & 63, lrow = lane & 15, lkg = lane >> 4;
  const int wave = tid >> 6, wm = wave >> 2, wn = wave & 3;
  const int aReg = wm * 16384;                 // this wave's A half-tile
  const int bReg = 32768 + (wn >> 1) * 16384;  // this wave's B half-tile
  const int brow0 = (wn & 1) * 64;             // row base within B half
  const int swz = (lrow & 7) << 4;

  // prologue: stage K-tile 0, drain, barrier
  stage_tile(g, 0, kt0);
  asm volatile("s_waitcnt vmcnt(0)" ::: "memory");
  __builtin_amdgcn_s_barrier();
  __builtin_amdgcn_sched_barrier(0);

  for (int t = 0; t < ktn; ++t) {
    const int d = t & 1;
    // stage next K-tile (clamped dup on last iter; lands in unread dbuf)
    stage_tile(g, d ^ 1, kt0 + imin(t + 1, ktn - 1));
    const char* db = lds + d * 65536;

    bf16x8v a[4][2], b0[2][2], b1[2][2];
#pragma unroll
    for (int nt = 0; nt < 2; ++nt)
#pragma unroll
      for (int ks = 0; ks < 2; ++ks) {
        const int ck = (ks * 64 + lkg * 16) ^ swz;
        b0[nt][ks] = *(const bf16x8v*)(db + bReg + (brow0 + nt * 16 + lrow) * 128 + ck);
        b1[nt][ks] = *(const bf16x8v*)(db + bReg + (brow0 + 32 + nt * 16 + lrow) * 128 + ck);
      }
    // ---- mh = 0 (wave rows 0-63) ----
#pragma unroll
    for (int mt = 0; mt < 4; ++mt)
#pragma unroll
      for (int ks = 0; ks < 2; ++ks)
        a[mt][ks] = *(const bf16x8v*)(db + aReg + (mt * 16 + lrow) * 128 + ((ks * 64 + lkg * 16) ^ swz));
    __builtin_amdgcn_s_setprio(1);
#pragma unroll
    for (int mt = 0; mt < 4; ++mt)
#pragma unroll
      for (int nt = 0; nt < 2; ++nt)
#pragma unroll
        for (int ks = 0; ks < 2; ++ks) {
          acc[0][0][mt][nt] = __builtin_amdgcn_mfma_f32_16x16x32_bf16(a[mt][ks], b0[nt][ks], acc[0][0][mt][nt], 0, 0, 0);
          acc[0][1][mt][nt] = __builtin_amdgcn_mfma_f32_16x16x32_bf16(a[mt][ks], b1[nt][ks], acc[0][1][mt][nt], 0, 0, 0);
        }
    __builtin_amdgcn_s_setprio(0);
    // ---- mh = 1 (wave rows 64-127) ----
#pragma unroll
    for (int mt = 0; mt < 4; ++mt)
#pragma unroll
      for (int ks = 0; ks < 2; ++ks)
        a[mt][ks] = *(const bf16x8v*)(db + aReg + ((64 + mt * 16 + lrow) * 128) + ((ks * 64 + lkg * 16) ^ swz));
    __builtin_amdgcn_s_setprio(1);
#pragma unroll
    for (int mt = 0; mt < 4; ++mt)
#pragma unroll
      for (int nt = 0; nt < 2; ++nt)
#pragma unroll
        for (int ks = 0; ks < 2; ++ks) {
          acc[1][1][mt][nt] = __builtin_amdgcn_mfma_f32_16x16x32_bf16(a[mt][ks], b1[nt][ks], acc[1][1][mt][nt], 0, 0, 0);
          acc[1][0][mt][nt] = __builtin_amdgcn_mfma_f32_16x16x32_bf16(a[mt][ks], b0[nt][ks], acc[1][0][mt][nt], 0, 0, 0);
        }
    __builtin_amdgcn_s_setprio(0);
    // boundary: next tile fully landed + all waves done reading this dbuf
    asm volatile("s_waitcnt vmcnt(0)" ::: "memory");
    __builtin_amdgcn_s_barrier();
    __builtin_amdgcn_sched_barrier(0);
  }
}

#define ACC256_INIT()                         \
  f32x4 acc[2][2][4][2];                      \
  {                                           \
    f32x4 z = {0.f, 0.f, 0.f, 0.f};           \
    for (int a1 = 0; a1 < 2; ++a1)            \
      for (int a2 = 0; a2 < 2; ++a2)          \
        for (int a3 = 0; a3 < 4; ++a3)        \
          for (int a4 = 0; a4 < 2; ++a4) acc[a1][a2][a3][a4] = z; \
  }

#define EPI_BASES()                                             \
  const int lane = threadIdx.x & 63;                            \
  const int wave = threadIdx.x >> 6;                            \
  const int wm = wave >> 2, wn = wave & 3;                      \
  const int rb = wm * 128 + ((lane >> 4) << 2);                 \
  const int cb = wn * 64 + (lane & 15);

// ---------------- QK projection: Q,K row-major bf16 ---------------------------
// grid 128 = 2z x 16bi x 4bj (bj inner), XCD-swizzled. K-tiles: 16.
__global__ __launch_bounds__(512, 2) void qk_kernel(const bf16* __restrict__ xb,
                                                    const bf16* __restrict__ Wq,
                                                    const bf16* __restrict__ Wk,
                                                    bf16* __restrict__ Q,
                                                    bf16* __restrict__ K) {
  extern __shared__ char lds[];
  const int l = xcd_swz(blockIdx.x, 128);
  const int z = l >> 6, tt = l & 63, bi = tt >> 2, bj = tt & 3;
  const bf16* W = (z == 0) ? Wq : Wk;
  ACC256_INIT();
  gemm256_core(xb, W, DIN, DIN, bi * 256, bj * 256, 0, 16, acc, lds);
  EPI_BASES();
  const int rbase = bi * 256 + rb, cbase = bj * 256 + cb;
  bf16* O = (z == 0) ? Q : K;
#pragma unroll
  for (int mh = 0; mh < 2; ++mh)
#pragma unroll
    for (int nh = 0; nh < 2; ++nh)
#pragma unroll
      for (int mt = 0; mt < 4; ++mt)
#pragma unroll
        for (int nt = 0; nt < 2; ++nt)
#pragma unroll
          for (int j = 0; j < 4; ++j)
            O[(size_t)(rbase + mh * 64 + mt * 16 + j) * DOUT + (cbase + nh * 32 + nt * 16)] =
                (bf16)acc[mh][nh][mt][nt][j];
}

// ---------------- scores (136 tri blocks) + V-projection (64 blocks) ----------
// grid 200, XCD-swizzled. Both classes co-resident: V-proj overlaps scores.
__global__ __launch_bounds__(512, 2) void scores_v_kernel(const bf16* __restrict__ Q,
                                                          const bf16* __restrict__ Km,
                                                          float* __restrict__ Sc,
                                                          const bf16* __restrict__ xb,
                                                          const bf16* __restrict__ Wv,
                                                          bf16* __restrict__ Vt) {
  extern __shared__ char lds[];
  const int l = xcd_swz(blockIdx.x, 200);
  if (l < 64) {
    // ---- V projection: out written transposed into Vt [1024][4096] ----
    const int bi = l >> 2, bj = l & 3;
    ACC256_INIT();
    gemm256_core(xb, Wv, DIN, DIN, bi * 256, bj * 256, 0, 16, acc, lds);
    EPI_BASES();
    const int rbase = bi * 256 + rb, cbase = bj * 256 + cb;
#pragma unroll
    for (int mh = 0; mh < 2; ++mh)
#pragma unroll
      for (int nh = 0; nh < 2; ++nh)
#pragma unroll
        for (int mt = 0; mt < 4; ++mt)
#pragma unroll
          for (int nt = 0; nt < 2; ++nt)
#pragma unroll
            for (int j = 0; j < 4; ++j)
              Vt[(size_t)(cbase + nh * 32 + nt * 16) * SEQ + (rbase + mh * 64 + mt * 16 + j)] =
                  (bf16)acc[mh][nh][mt][nt][j];
  } else {
    // ---- scores tile (triangular) ----
    const int t = l - 64;
    int bi = (int)((sqrtf(8.0f * (float)t + 1.0f) - 1.0f) * 0.5f);
    while ((bi + 1) * (bi + 2) / 2 <= t) ++bi;
    while (bi * (bi + 1) / 2 > t) --bi;
    const int bj = t - bi * (bi + 1) / 2;
    ACC256_INIT();
    gemm256_core(Q, Km, DOUT, DOUT, bi * 256, bj * 256, 0, 16, acc, lds);
    EPI_BASES();
    const int rbase = bi * 256 + rb, cbase = bj * 256 + cb;
    const float scale = 0.03125f;  // 1/sqrt(1024)
#pragma unroll
    for (int mh = 0; mh < 2; ++mh)
#pragma unroll
      for (int nh = 0; nh < 2; ++nh)
#pragma unroll
        for (int mt = 0; mt < 4; ++mt)
#pragma unroll
          for (int nt = 0; nt < 2; ++nt)
#pragma unroll
            for (int j = 0; j < 4; ++j)
              Sc[(size_t)(rbase + mh * 64 + mt * 16 + j) * SEQ + (cbase + nh * 32 + nt * 16)] =
                  acc[mh][nh][mt][nt][j] * scale;
  }
}

// ---------------- row softmax (vectorized): zero-pad to 256-col boundary ------
__global__ __launch_bounds__(256) void softmax_kernel(const float* __restrict__ Sc,
                                                      bf16* __restrict__ P) {
  __shared__ float rowbuf[SEQ];
  __shared__ float red[8];
  const int r = blockIdx.x;
  const int n = r + 1;
  const int nw4 = ((r >> 8) + 1) << 6;  // padded row length / 4 (256-col blocks)
  const int tid = threadIdx.x;
  const float* src = Sc + (size_t)r * SEQ;
  const float NEG = -__builtin_inff();

  float lmax = NEG;
  for (int g = tid; g < nw4; g += 256) {
    float4 v = reinterpret_cast<const float4*>(src)[g];
    const int b = g * 4;
    v.x = (b + 0 < n) ? v.x : NEG;
    v.y = (b + 1 < n) ? v.y : NEG;
    v.z = (b + 2 < n) ? v.z : NEG;
    v.w = (b + 3 < n) ? v.w : NEG;
    reinterpret_cast<float4*>(rowbuf)[g] = v;
    lmax = fmaxf(fmaxf(lmax, fmaxf(v.x, v.y)), fmaxf(v.z, v.w));
  }
#pragma unroll
  for (int m = 32; m >= 1; m >>= 1) lmax = fmaxf(lmax, __shfl_xor(lmax, m, 64));
  if ((tid & 63) == 0) red[tid >> 6] = lmax;
  __syncthreads();
  const float rmax = fmaxf(fmaxf(red[0], red[1]), fmaxf(red[2], red[3]));

  float lsum = 0.f;
  for (int g = tid; g < nw4; g += 256) {
    float4 v = reinterpret_cast<const float4*>(rowbuf)[g];
    v.x = __expf(v.x - rmax);
    v.y = __expf(v.y - rmax);
    v.z = __expf(v.z - rmax);
    v.w = __expf(v.w - rmax);
    reinterpret_cast<float4*>(rowbuf)[g] = v;
    lsum += v.x + v.y + v.z + v.w;
  }
#pragma unroll
  for (int m = 32; m >= 1; m >>= 1) lsum += __shfl_xor(lsum, m, 64);
  if ((tid & 63) == 0) red[4 + (tid >> 6)] = lsum;
  __syncthreads();
  const float inv = 1.0f / (red[4] + red[5] + red[6] + red[7]);

  bf16* dst = P + (size_t)r * SEQ;
  for (int g = tid; g < nw4; g += 256) {
    float4 v = reinterpret_cast<const float4*>(rowbuf)[g];
    bf16x4v o;
    o[0] = (bf16)(v.x * inv);
    o[1] = (bf16)(v.y * inv);
    o[2] = (bf16)(v.z * inv);
    o[3] = (bf16)(v.w * inv);
    *reinterpret_cast<bf16x4v*>(dst + g * 4) = o;
  }
}

// ---------------- out = P @ V, split-K WITHOUT atomics ------------------------
// grid 204 = 51 chunk-slots x 4 bj, XCD-swizzled. nch(bi)=ceil((bi+1)/3), <=12
// K-tiles per chunk. LAST chunk stores direct to Out (full coverage, no memset);
// earlier chunks store fp32 partial tiles into dead Sc space (35 slots x 4bj
// x 256KB = 36.7MB <= 64MB). reduce_kernel sums partials into Out afterwards.
__device__ __constant__ int kPref[13] = {0, 1, 2, 3, 5, 7, 9, 12, 15, 18, 22, 26, 30};

__global__ __launch_bounds__(512, 2) void pv_kernel(const bf16* __restrict__ P,
                                                    const bf16* __restrict__ Vt,
                                                    float* __restrict__ Out,
                                                    float* __restrict__ Par) {
  extern __shared__ char lds[];
  const int l = xcd_swz(blockIdx.x, 204);
  const int bj = l & 3;
  int c = l >> 2, bi = 0;
  for (;;) {
    const int nch = (bi + 3) / 3;  // ceil((bi+1)/3)
    if (c < nch) break;
    c -= nch; ++bi;
  }
  const int nch = (bi + 3) / 3;
  const int Ti = (bi + 1) * 4;
  const int base = Ti / nch, rem = Ti % nch;
  const int kt0 = c * base + imin(c, rem);
  const int ktn = base + (c < rem ? 1 : 0);
  ACC256_INIT();
  gemm256_core(P, Vt, SEQ, SEQ, bi * 256, bj * 256, kt0, ktn, acc, lds);
  EPI_BASES();
  if (c == nch - 1) {
    // direct store (covers every Out element exactly once across the grid)
    const int rbase = bi * 256 + rb, cbase = bj * 256 + cb;
#pragma unroll
    for (int mh = 0; mh < 2; ++mh)
#pragma unroll
      for (int nh = 0; nh < 2; ++nh)
#pragma unroll
        for (int mt = 0; mt < 4; ++mt)
#pragma unroll
          for (int nt = 0; nt < 2; ++nt)
#pragma unroll
            for (int j = 0; j < 4; ++j)
              Out[(size_t)(rbase + mh * 64 + mt * 16 + j) * DOUT + (cbase + nh * 32 + nt * 16)] =
                  acc[mh][nh][mt][nt][j];
  } else {
    // partial tile, row-major 256x256 fp32
    const int slot = (kPref[bi - 3] + c) * 4 + bj;
    float* Pp = Par + (size_t)slot * 65536;
#pragma unroll
    for (int mh = 0; mh < 2; ++mh)
#pragma unroll
      for (int nh = 0; nh < 2; ++nh)
#pragma unroll
        for (int mt = 0; mt < 4; ++mt)
#pragma unroll
          for (int nt = 0; nt < 2; ++nt)
#pragma unroll
            for (int j = 0; j < 4; ++j)
              Pp[(rb + mh * 64 + mt * 16 + j) * 256 + (cb + nh * 32 + nt * 16)] =
                  acc[mh][nh][mt][nt][j];
  }
}

// ---------------- reduction: Out[tile] += sum of its partials -----------------
// grid 52 tiles x 64 sub-blocks = 3328, 256 thr, one float4/thread.
__global__ __launch_bounds__(256) void reduce_kernel(const float* __restrict__ Par,
                                                     float* __restrict__ Out) {
  const int blk = blockIdx.x;
  const int t2 = blk >> 6, sub = blk & 63;
  const int bi = 3 + (t2 >> 2), bj = t2 & 3;
  const int npart = (bi + 3) / 3 - 1;         // 1..5
  const int pb = kPref[bi - 3] * 4 + bj;      // partial c at slot pb + c*4
  const int elem = sub * 1024 + threadIdx.x * 4;
  const int r = elem >> 8, cc = elem & 255;
  float* op = Out + (size_t)(bi * 256 + r) * DOUT + bj * 256 + cc;
  float4 o = *reinterpret_cast<float4*>(op);
  for (int p = 0; p < npart; ++p) {
    const float4 v = *reinterpret_cast<const float4*>(Par + (size_t)(pb + p * 4) * 65536 + elem);
    o.x += v.x; o.y += v.y; o.z += v.z; o.w += v.w;
  }
  *reinterpret_cast<float4*>(op) = o;
}

extern "C" void kernel_launch(void* const* d_in, const int* in_sizes, int n_in,
                              void* d_out, int out_size, void* d_ws, size_t ws_size,
                              hipStream_t stream) {
  const float* x  = (const float*)d_in[0];
  const float* Wq = (const float*)d_in[1];
  const float* Wk = (const float*)d_in[2];
  const float* Wv = (const float*)d_in[3];
  float* Out = (float*)d_out;

  char* base = (char*)d_ws;
  bf16* xb  = (bf16*)(base + 0);          //  8 MB  [4096x1024]
  bf16* wqb = (bf16*)(base + 8388608);    //  2 MB
  bf16* wkb = (bf16*)(base + 10485760);   //  2 MB
  bf16* wvb = (bf16*)(base + 12582912);   //  2 MB
  bf16* Qb  = (bf16*)(base + 14680064);   //  8 MB
  bf16* Kb  = (bf16*)(base + 23068672);   //  8 MB
  bf16* Vtb = (bf16*)(base + 31457280);   //  8 MB  [1024x4096] transposed
  float* Sc = (float*)(base + 39845888);  // 64 MB  [4096x4096] fp32; dead after
                                          //        softmax -> reused as Par
  bf16* P   = (bf16*)(base + 106954752);  // 32 MB  [4096x4096] bf16

  (void)hipFuncSetAttribute((const void*)qk_kernel,
                            hipFuncAttributeMaxDynamicSharedMemorySize, 131072);
  (void)hipFuncSetAttribute((const void*)scores_v_kernel,
                            hipFuncAttributeMaxDynamicSharedMemorySize, 131072);
  (void)hipFuncSetAttribute((const void*)pv_kernel,
                            hipFuncAttributeMaxDynamicSharedMemorySize, 131072);

  cast_all_kernel<<<7168, 256, 0, stream>>>(x, Wq, Wk, Wv, xb, wqb, wkb, wvb);

  qk_kernel<<<128, 512, 131072, stream>>>(xb, wqb, wkb, Qb, Kb);
  scores_v_kernel<<<200, 512, 131072, stream>>>(Qb, Kb, Sc, xb, wvb, Vtb);
  softmax_kernel<<<SEQ, 256, 0, stream>>>(Sc, P);
  pv_kernel<<<204, 512, 131072, stream>>>(P, Vtb, Out, Sc);
  reduce_kernel<<<3328, 256, 0, stream>>>(Sc, Out);
}